// Round 2
// baseline (721.190 us; speedup 1.0000x reference)
//
#include <hip/hip_runtime.h>
#include <math.h>

#define D 512
#define K3D 1536
#define NEGF (-3.40282346638528859812e+38f)

typedef __bf16 bf16x8 __attribute__((ext_vector_type(8)));
typedef unsigned short ushort8v __attribute__((ext_vector_type(8)));
typedef float f32x4 __attribute__((ext_vector_type(4)));

__device__ __forceinline__ unsigned short f2bf(float f) {
    unsigned int u = __float_as_uint(f);
    unsigned int r = (u + 0x7FFFu + ((u >> 16) & 1u)) >> 16;
    return (unsigned short)r;
}

__device__ __forceinline__ int lower_bound_dev(const int* __restrict__ b, int n, int v) {
    int lo = 0, hi = n;
    while (lo < hi) {
        int mid = (lo + hi) >> 1;
        if (b[mid] < v) lo = mid + 1; else hi = mid;
    }
    return lo;
}

__device__ __forceinline__ void acc4(float4& s, float4& q, float4& m, const float4 v) {
    s.x += v.x; s.y += v.y; s.z += v.z; s.w += v.w;
    q.x = fmaf(v.x, v.x, q.x); q.y = fmaf(v.y, v.y, q.y);
    q.z = fmaf(v.z, v.z, q.z); q.w = fmaf(v.w, v.w, q.w);
    m.x = fmaxf(m.x, v.x); m.y = fmaxf(m.y, v.y);
    m.z = fmaxf(m.z, v.z); m.w = fmaxf(m.w, v.w);
}

// One block per segment. 512 threads: col = tid&127 (float4 col), rg = tid>>7
// (row-parity group 0..3). DIAGNOSTIC ROUND: this kernel is launched 3x
// (idempotent) so that dur_us delta = 2x its true duration, which the
// rocprof top-5 cutoff has been hiding.
__global__ __launch_bounds__(512) void pool_kernel(
    const float* __restrict__ x, const int* __restrict__ batch,
    unsigned short* __restrict__ pooled_b, int n) {
    const int s   = blockIdx.x;
    const int col = threadIdx.x & 127;
    const int rg  = threadIdx.x >> 7;   // 0..3
    const int start = lower_bound_dev(batch, n, s);
    const int end   = lower_bound_dev(batch, n, s + 1);

    const float4* __restrict__ xv = (const float4*)x;  // row stride = 128 float4

    float4 sum = {0.f, 0.f, 0.f, 0.f};
    float4 sq  = {0.f, 0.f, 0.f, 0.f};
    float4 mx  = {-INFINITY, -INFINITY, -INFINITY, -INFINITY};

    int i = start + rg;
    for (; i + 12 < end; i += 16) {
        float4 v0 = xv[(size_t)(i + 0)  * 128 + col];
        float4 v1 = xv[(size_t)(i + 4)  * 128 + col];
        float4 v2 = xv[(size_t)(i + 8)  * 128 + col];
        float4 v3 = xv[(size_t)(i + 12) * 128 + col];
        acc4(sum, sq, mx, v0);
        acc4(sum, sq, mx, v1);
        acc4(sum, sq, mx, v2);
        acc4(sum, sq, mx, v3);
    }
    for (; i < end; i += 4) {
        float4 v0 = xv[(size_t)i * 128 + col];
        acc4(sum, sq, mx, v0);
    }

    // Combine the 4 row-parity groups: groups 1..3 stash, group 0 merges.
    __shared__ __align__(16) float4 red[9 * 128];   // 18 KB
    if (rg > 0) {
        const int base = (rg - 1) * 384;
        red[base + col]       = sum;
        red[base + 128 + col] = sq;
        red[base + 256 + col] = mx;
    }
    __syncthreads();
    if (rg == 0) {
#pragma unroll
        for (int g = 0; g < 3; ++g) {
            const int base = g * 384;
            float4 s2 = red[base + col];
            float4 q2 = red[base + 128 + col];
            float4 m2 = red[base + 256 + col];
            sum.x += s2.x; sum.y += s2.y; sum.z += s2.z; sum.w += s2.w;
            sq.x  += q2.x; sq.y  += q2.y; sq.z  += q2.z; sq.w  += q2.w;
            mx.x = fmaxf(mx.x, m2.x); mx.y = fmaxf(mx.y, m2.y);
            mx.z = fmaxf(mx.z, m2.z); mx.w = fmaxf(mx.w, m2.w);
        }

        const float cnt  = (float)(end - start);
        const float inv  = 1.f / fmaxf(cnt, 1.f);
        const float dinv = 1.f / fmaxf(cnt - 1.f, 1.f);

        float4 mean, stdv;
        mean.x = sum.x * inv; mean.y = sum.y * inv;
        mean.z = sum.z * inv; mean.w = sum.w * inv;

        float vx = (sq.x - mean.x * sum.x) * dinv;
        float vy = (sq.y - mean.y * sum.y) * dinv;
        float vz = (sq.z - mean.z * sum.z) * dinv;
        float vw = (sq.w - mean.w * sum.w) * dinv;
        vx = fmaxf(vx, 0.f); vy = fmaxf(vy, 0.f);
        vz = fmaxf(vz, 0.f); vw = fmaxf(vw, 0.f);
        stdv.x = vx > 0.f ? sqrtf(vx) : 0.f;
        stdv.y = vy > 0.f ? sqrtf(vy) : 0.f;
        stdv.z = vz > 0.f ? sqrtf(vz) : 0.f;
        stdv.w = vw > 0.f ? sqrtf(vw) : 0.f;

        float mxx = isfinite(mx.x) ? mx.x : NEGF;
        float mxy = isfinite(mx.y) ? mx.y : NEGF;
        float mxz = isfinite(mx.z) ? mx.z : NEGF;
        float mxw = isfinite(mx.w) ? mx.w : NEGF;

        unsigned short* prow = pooled_b + (size_t)s * K3D;
        ushort4 om = { f2bf(mean.x), f2bf(mean.y), f2bf(mean.z), f2bf(mean.w) };
        ushort4 ox = { f2bf(mxx),    f2bf(mxy),    f2bf(mxz),    f2bf(mxw)    };
        ushort4 os = { f2bf(stdv.x), f2bf(stdv.y), f2bf(stdv.z), f2bf(stdv.w) };
        *(ushort4*)&prow[4 * col]        = om;
        *(ushort4*)&prow[512 + 4 * col]  = ox;
        *(ushort4*)&prow[1024 + 4 * col] = os;
    }
}

// Transpose-convert W [1536,512] fp32 -> Wt [512,1536] bf16 (row n holds W[:,n]).
__global__ __launch_bounds__(256) void wconv_kernel(
    const float* __restrict__ W, unsigned short* __restrict__ Wt) {
    __shared__ float tile[32][33];
    const int c0 = blockIdx.x * 32;  // over N=512
    const int r0 = blockIdx.y * 32;  // over K=1536
    const int t = threadIdx.x;
    const int r = t >> 3, c4 = (t & 7) * 4;
    float4 v = *(const float4*)&W[(size_t)(r0 + r) * D + c0 + c4];
    tile[r][c4 + 0] = v.x; tile[r][c4 + 1] = v.y;
    tile[r][c4 + 2] = v.z; tile[r][c4 + 3] = v.w;
    __syncthreads();
    const int nn = t >> 3, k4 = (t & 7) * 4;
    ushort4 o = { f2bf(tile[k4 + 0][nn]), f2bf(tile[k4 + 1][nn]),
                  f2bf(tile[k4 + 2][nn]), f2bf(tile[k4 + 3][nn]) };
    *(ushort4*)&Wt[(size_t)(c0 + nn) * K3D + r0 + k4] = o;
}

// bf16 MFMA GEMM with split-K:
// Hp[z][M,512] = pooled_b[M, kz] @ Wt[kz, 512]^T-style (Wt rows are W columns).
// 64x64 tile, BK=64, 256 threads (4 waves, each 32x32 = 2x2 of 16x16x32 MFMA).
#define GBM 64
#define GBN 64
#define GBK 64
#define LDT 88     // bf16 elements; row stride 176 B -> bank starts 12r%32, <=2-way
#define GSPLIT 4
#define GKC (K3D / GSPLIT)  // 384

__global__ __launch_bounds__(256) void mfma_gemm(
    const unsigned short* __restrict__ A,   // pooled bf16 [M, 1536]
    const unsigned short* __restrict__ B,   // Wt bf16 [512, 1536]
    float* __restrict__ Hp, int S) {
    __shared__ unsigned short As[GBM * LDT];
    __shared__ unsigned short Bs[GBN * LDT];

    const int tid  = threadIdx.x;
    const int wave = tid >> 6;
    const int lane = tid & 63;
    const int m0 = blockIdx.y * GBM;
    const int n0 = blockIdx.x * GBN;
    const int kb = blockIdx.z * GKC;
    const int wm = (wave & 1) * 32;
    const int wn = (wave >> 1) * 32;

    const int sr = tid >> 3;         // staging row 0..31 (and +32)
    const int sc = (tid & 7) * 8;    // staging col (bf16), 16 B chunks

    const int frow = lane & 15;          // m (or n) within 16-tile
    const int fk   = (lane >> 4) * 8;    // k offset within 32

    f32x4 acc00 = {0.f, 0.f, 0.f, 0.f};
    f32x4 acc01 = {0.f, 0.f, 0.f, 0.f};
    f32x4 acc10 = {0.f, 0.f, 0.f, 0.f};
    f32x4 acc11 = {0.f, 0.f, 0.f, 0.f};

    for (int k0 = kb; k0 < kb + GKC; k0 += GBK) {
        ushort8v a0 = *(const ushort8v*)&A[(size_t)(m0 + sr)      * K3D + k0 + sc];
        ushort8v a1 = *(const ushort8v*)&A[(size_t)(m0 + sr + 32) * K3D + k0 + sc];
        ushort8v b0 = *(const ushort8v*)&B[(size_t)(n0 + sr)      * K3D + k0 + sc];
        ushort8v b1 = *(const ushort8v*)&B[(size_t)(n0 + sr + 32) * K3D + k0 + sc];
        __syncthreads();
        *(ushort8v*)&As[(sr)      * LDT + sc] = a0;
        *(ushort8v*)&As[(sr + 32) * LDT + sc] = a1;
        *(ushort8v*)&Bs[(sr)      * LDT + sc] = b0;
        *(ushort8v*)&Bs[(sr + 32) * LDT + sc] = b1;
        __syncthreads();

#pragma unroll
        for (int ks = 0; ks < GBK; ks += 32) {
            bf16x8 af0 = *(const bf16x8*)&As[(wm + frow)      * LDT + ks + fk];
            bf16x8 af1 = *(const bf16x8*)&As[(wm + 16 + frow) * LDT + ks + fk];
            bf16x8 bv0 = *(const bf16x8*)&Bs[(wn + frow)      * LDT + ks + fk];
            bf16x8 bv1 = *(const bf16x8*)&Bs[(wn + 16 + frow) * LDT + ks + fk];
            acc00 = __builtin_amdgcn_mfma_f32_16x16x32_bf16(af0, bv0, acc00, 0, 0, 0);
            acc01 = __builtin_amdgcn_mfma_f32_16x16x32_bf16(af0, bv1, acc01, 0, 0, 0);
            acc10 = __builtin_amdgcn_mfma_f32_16x16x32_bf16(af1, bv0, acc10, 0, 0, 0);
            acc11 = __builtin_amdgcn_mfma_f32_16x16x32_bf16(af1, bv1, acc11, 0, 0, 0);
        }
    }

    float* out = Hp + (size_t)blockIdx.z * S * D;
    const int orow = (lane >> 4) * 4;   // + reg index
    const int ocol = lane & 15;
#pragma unroll
    for (int r = 0; r < 4; ++r) {
        out[(size_t)(m0 + wm +      orow + r) * D + n0 + wn +      ocol] = acc00[r];
        out[(size_t)(m0 + wm +      orow + r) * D + n0 + wn + 16 + ocol] = acc01[r];
        out[(size_t)(m0 + wm + 16 + orow + r) * D + n0 + wn +      ocol] = acc10[r];
        out[(size_t)(m0 + wm + 16 + orow + r) * D + n0 + wn + 16 + ocol] = acc11[r];
    }
}

// Reduce GSPLIT split-K partials + bias, then LayerNorm + affine + LeakyReLU.
__global__ __launch_bounds__(128) void ln_kernel(
    const float* __restrict__ Hp, const float* __restrict__ bias,
    const float* __restrict__ gamma, const float* __restrict__ beta,
    float* __restrict__ out, int S) {
    const int row = blockIdx.x;
    const int tid = threadIdx.x;
    const size_t idx = (size_t)row * 128 + tid;  // float4 index into [S,D]
    const size_t stride = (size_t)S * 128;       // float4 stride per partial

    const float4* hp = (const float4*)Hp;
    float4 v0 = hp[idx];
    float4 v1 = hp[idx + stride];
    float4 v2 = hp[idx + 2 * stride];
    float4 v3 = hp[idx + 3 * stride];
    float4 bb = *(const float4*)&bias[4 * tid];
    float4 v;
    v.x = (v0.x + v1.x) + (v2.x + v3.x) + bb.x;
    v.y = (v0.y + v1.y) + (v2.y + v3.y) + bb.y;
    v.z = (v0.z + v1.z) + (v2.z + v3.z) + bb.z;
    v.w = (v0.w + v1.w) + (v2.w + v3.w) + bb.w;

    float s = v.x + v.y + v.z + v.w;
    float q = v.x * v.x + v.y * v.y + v.z * v.z + v.w * v.w;
#pragma unroll
    for (int off = 32; off > 0; off >>= 1) {
        s += __shfl_down(s, off);
        q += __shfl_down(q, off);
    }
    __shared__ float ls[2], lq[2];
    const int wave = tid >> 6, lane = tid & 63;
    if (lane == 0) { ls[wave] = s; lq[wave] = q; }
    __syncthreads();
    s = ls[0] + ls[1];
    q = lq[0] + lq[1];

    const float mu = s * (1.f / 512.f);
    float var = q * (1.f / 512.f) - mu * mu;
    var = fmaxf(var, 0.f);
    const float r = rsqrtf(var + 1e-5f);

    float4 g  = *(const float4*)&gamma[4 * tid];
    float4 bt = *(const float4*)&beta[4 * tid];
    float4 o;
    o.x = (v.x - mu) * r * g.x + bt.x;
    o.y = (v.y - mu) * r * g.y + bt.y;
    o.z = (v.z - mu) * r * g.z + bt.z;
    o.w = (v.w - mu) * r * g.w + bt.w;
    o.x = o.x >= 0.f ? o.x : 0.01f * o.x;
    o.y = o.y >= 0.f ? o.y : 0.01f * o.y;
    o.z = o.z >= 0.f ? o.z : 0.01f * o.z;
    o.w = o.w >= 0.f ? o.w : 0.01f * o.w;
    *(float4*)&out[(size_t)row * D + 4 * tid] = o;
}

extern "C" void kernel_launch(void* const* d_in, const int* in_sizes, int n_in,
                              void* d_out, int out_size, void* d_ws, size_t ws_size,
                              hipStream_t stream) {
    const float* x     = (const float*)d_in[0];
    const float* W     = (const float*)d_in[1];
    const float* b     = (const float*)d_in[2];
    const float* gamma = (const float*)d_in[3];
    const float* beta  = (const float*)d_in[4];
    const int*   batch = (const int*)d_in[5];
    const int n = in_sizes[5];
    const int S = out_size / D;  // 1024

    char* ws = (char*)d_ws;
    unsigned short* pooled_b = (unsigned short*)ws;                       // [S,1536] bf16, 3 MB
    unsigned short* Wt       = (unsigned short*)(ws + (size_t)S * K3D * 2);          // [512,1536] bf16
    float*          Hp       = (float*)(ws + (size_t)S * K3D * 2 + (size_t)D * K3D * 2);  // [GSPLIT,S,512] f32
    float* out = (float*)d_out;

    // DIAGNOSTIC: pool launched 3x (idempotent). dur_us delta vs round 1
    // equals 2x pool's true duration. H_fast predicts +90..140 us total;
    // H_slow predicts +~480 us and pool dispatches entering rocprof top-5.
    pool_kernel<<<S, 512, 0, stream>>>(x, batch, pooled_b, n);
    pool_kernel<<<S, 512, 0, stream>>>(x, batch, pooled_b, n);
    pool_kernel<<<S, 512, 0, stream>>>(x, batch, pooled_b, n);
    dim3 gw(D / 32, K3D / 32);  // (16, 48)
    wconv_kernel<<<gw, 256, 0, stream>>>(W, Wt);
    dim3 gg(D / GBN, S / GBM, GSPLIT);  // (8, 16, 4)
    mfma_gemm<<<gg, 256, 0, stream>>>(pooled_b, Wt, Hp, S);
    ln_kernel<<<S, 128, 0, stream>>>(Hp, b, gamma, beta, out, S);
}

// Round 3
// 530.622 us; speedup vs baseline: 1.3591x; 1.3591x over previous
//
#include <hip/hip_runtime.h>
#include <math.h>

#define D 512
#define K3D 1536
#define NEGF (-3.40282346638528859812e+38f)

typedef __bf16 bf16x8 __attribute__((ext_vector_type(8)));
typedef unsigned short ushort8v __attribute__((ext_vector_type(8)));
typedef float f32x4 __attribute__((ext_vector_type(4)));

__device__ __forceinline__ unsigned short f2bf(float f) {
    unsigned int u = __float_as_uint(f);
    unsigned int r = (u + 0x7FFFu + ((u >> 16) & 1u)) >> 16;
    return (unsigned short)r;
}

__device__ __forceinline__ int lower_bound_dev(const int* __restrict__ b, int n, int v) {
    int lo = 0, hi = n;
    while (lo < hi) {
        int mid = (lo + hi) >> 1;
        if (b[mid] < v) lo = mid + 1; else hi = mid;
    }
    return lo;
}

__device__ __forceinline__ void acc4(f32x4& s, f32x4& q, f32x4& m, const f32x4 v) {
    s[0] += v[0]; s[1] += v[1]; s[2] += v[2]; s[3] += v[3];
    q[0] = fmaf(v[0], v[0], q[0]); q[1] = fmaf(v[1], v[1], q[1]);
    q[2] = fmaf(v[2], v[2], q[2]); q[3] = fmaf(v[3], v[3], q[3]);
    m[0] = fmaxf(m[0], v[0]); m[1] = fmaxf(m[1], v[1]);
    m[2] = fmaxf(m[2], v[2]); m[3] = fmaxf(m[3], v[3]);
}

// Precompute segment boundaries: bounds[s] = lower_bound(batch, s), s in [0, S].
// Removes the 2x18-iteration dependent binary search from every pool block.
__global__ __launch_bounds__(256) void bounds_kernel(
    const int* __restrict__ batch, int* __restrict__ bounds, int n, int S) {
    const int s = blockIdx.x * 256 + threadIdx.x;
    if (s <= S) bounds[s] = lower_bound_dev(batch, n, s);
}

// Fused: blocks [0, S) pool one segment each (512 threads, 4 row-parity
// groups); blocks [S, S + 384) transpose-convert W tiles (64x32, 512 thr).
// Pool uses nontemporal loads: x is streamed exactly once, 410 MB >> L3.
__global__ __launch_bounds__(512) void pool_wconv_kernel(
    const float* __restrict__ x, const int* __restrict__ bounds,
    unsigned short* __restrict__ pooled_b,
    const float* __restrict__ W, unsigned short* __restrict__ Wt, int S) {
    __shared__ __align__(16) f32x4 red[9 * 128];   // pool reduction, 18 KB
    __shared__ float tile[64][33];                 // wconv transpose staging

    if ((int)blockIdx.x < S) {
        // ---------------- pool path ----------------
        const int s   = blockIdx.x;
        const int col = threadIdx.x & 127;
        const int rg  = threadIdx.x >> 7;   // 0..3
        const int start = bounds[s];
        const int end   = bounds[s + 1];

        const f32x4* __restrict__ xv = (const f32x4*)x;  // row stride = 128 f32x4

        f32x4 sum = {0.f, 0.f, 0.f, 0.f};
        f32x4 sq  = {0.f, 0.f, 0.f, 0.f};
        f32x4 mx  = {-INFINITY, -INFINITY, -INFINITY, -INFINITY};

        int i = start + rg;
        for (; i + 12 < end; i += 16) {
            f32x4 v0 = __builtin_nontemporal_load(&xv[(size_t)(i + 0)  * 128 + col]);
            f32x4 v1 = __builtin_nontemporal_load(&xv[(size_t)(i + 4)  * 128 + col]);
            f32x4 v2 = __builtin_nontemporal_load(&xv[(size_t)(i + 8)  * 128 + col]);
            f32x4 v3 = __builtin_nontemporal_load(&xv[(size_t)(i + 12) * 128 + col]);
            acc4(sum, sq, mx, v0);
            acc4(sum, sq, mx, v1);
            acc4(sum, sq, mx, v2);
            acc4(sum, sq, mx, v3);
        }
        for (; i < end; i += 4) {
            f32x4 v0 = __builtin_nontemporal_load(&xv[(size_t)i * 128 + col]);
            acc4(sum, sq, mx, v0);
        }

        if (rg > 0) {
            const int base = (rg - 1) * 384;
            red[base + col]       = sum;
            red[base + 128 + col] = sq;
            red[base + 256 + col] = mx;
        }
        __syncthreads();
        if (rg == 0) {
#pragma unroll
            for (int g = 0; g < 3; ++g) {
                const int base = g * 384;
                f32x4 s2 = red[base + col];
                f32x4 q2 = red[base + 128 + col];
                f32x4 m2 = red[base + 256 + col];
                sum[0] += s2[0]; sum[1] += s2[1]; sum[2] += s2[2]; sum[3] += s2[3];
                sq[0]  += q2[0]; sq[1]  += q2[1]; sq[2]  += q2[2]; sq[3]  += q2[3];
                mx[0] = fmaxf(mx[0], m2[0]); mx[1] = fmaxf(mx[1], m2[1]);
                mx[2] = fmaxf(mx[2], m2[2]); mx[3] = fmaxf(mx[3], m2[3]);
            }

            const float cnt  = (float)(end - start);
            const float inv  = 1.f / fmaxf(cnt, 1.f);
            const float dinv = 1.f / fmaxf(cnt - 1.f, 1.f);

            float mean[4], stdv[4], mxo[4];
#pragma unroll
            for (int j = 0; j < 4; ++j) {
                mean[j] = sum[j] * inv;
                float v = (sq[j] - mean[j] * sum[j]) * dinv;
                v = fmaxf(v, 0.f);
                stdv[j] = v > 0.f ? sqrtf(v) : 0.f;
                mxo[j]  = isfinite(mx[j]) ? mx[j] : NEGF;
            }

            unsigned short* prow = pooled_b + (size_t)s * K3D;
            ushort4 om = { f2bf(mean[0]), f2bf(mean[1]), f2bf(mean[2]), f2bf(mean[3]) };
            ushort4 ox = { f2bf(mxo[0]),  f2bf(mxo[1]),  f2bf(mxo[2]),  f2bf(mxo[3])  };
            ushort4 os = { f2bf(stdv[0]), f2bf(stdv[1]), f2bf(stdv[2]), f2bf(stdv[3]) };
            *(ushort4*)&prow[4 * col]        = om;
            *(ushort4*)&prow[512 + 4 * col]  = ox;
            *(ushort4*)&prow[1024 + 4 * col] = os;
        }
    } else {
        // ---------------- wconv path ----------------
        // W [1536,512] fp32 -> Wt [512,1536] bf16 (row n holds W[:,n]).
        // 64 (K) x 32 (N) tile per block, 512 threads.
        const int bid = (int)blockIdx.x - S;
        const int c0 = (bid & 15) * 32;   // over N=512 (16 chunks)
        const int r0 = (bid >> 4) * 64;   // over K=1536 (24 chunks)
        const int t = threadIdx.x;
        const int r = t >> 3, c4 = (t & 7) * 4;
        float4 v = *(const float4*)&W[(size_t)(r0 + r) * D + c0 + c4];
        tile[r][c4 + 0] = v.x; tile[r][c4 + 1] = v.y;
        tile[r][c4 + 2] = v.z; tile[r][c4 + 3] = v.w;
        __syncthreads();
        const int nn = t >> 4, k4 = (t & 15) * 4;
        ushort4 o = { f2bf(tile[k4 + 0][nn]), f2bf(tile[k4 + 1][nn]),
                      f2bf(tile[k4 + 2][nn]), f2bf(tile[k4 + 3][nn]) };
        *(ushort4*)&Wt[(size_t)(c0 + nn) * K3D + r0 + k4] = o;
    }
}

// bf16 MFMA GEMM with split-K:
// Hp[z][M,512] = pooled_b[M, kz] @ Wt[kz, 512]^T-style (Wt rows are W columns).
// 64x64 tile, BK=64, 256 threads (4 waves, each 32x32 = 2x2 of 16x16x32 MFMA).
#define GBM 64
#define GBN 64
#define GBK 64
#define LDT 88     // bf16 elements; row stride 176 B -> bank starts 12r%32, <=2-way
#define GSPLIT 4
#define GKC (K3D / GSPLIT)  // 384

__global__ __launch_bounds__(256) void mfma_gemm(
    const unsigned short* __restrict__ A,   // pooled bf16 [M, 1536]
    const unsigned short* __restrict__ B,   // Wt bf16 [512, 1536]
    float* __restrict__ Hp, int S) {
    __shared__ unsigned short As[GBM * LDT];
    __shared__ unsigned short Bs[GBN * LDT];

    const int tid  = threadIdx.x;
    const int wave = tid >> 6;
    const int lane = tid & 63;
    const int m0 = blockIdx.y * GBM;
    const int n0 = blockIdx.x * GBN;
    const int kb = blockIdx.z * GKC;
    const int wm = (wave & 1) * 32;
    const int wn = (wave >> 1) * 32;

    const int sr = tid >> 3;         // staging row 0..31 (and +32)
    const int sc = (tid & 7) * 8;    // staging col (bf16), 16 B chunks

    const int frow = lane & 15;          // m (or n) within 16-tile
    const int fk   = (lane >> 4) * 8;    // k offset within 32

    f32x4 acc00 = {0.f, 0.f, 0.f, 0.f};
    f32x4 acc01 = {0.f, 0.f, 0.f, 0.f};
    f32x4 acc10 = {0.f, 0.f, 0.f, 0.f};
    f32x4 acc11 = {0.f, 0.f, 0.f, 0.f};

    for (int k0 = kb; k0 < kb + GKC; k0 += GBK) {
        ushort8v a0 = *(const ushort8v*)&A[(size_t)(m0 + sr)      * K3D + k0 + sc];
        ushort8v a1 = *(const ushort8v*)&A[(size_t)(m0 + sr + 32) * K3D + k0 + sc];
        ushort8v b0 = *(const ushort8v*)&B[(size_t)(n0 + sr)      * K3D + k0 + sc];
        ushort8v b1 = *(const ushort8v*)&B[(size_t)(n0 + sr + 32) * K3D + k0 + sc];
        __syncthreads();
        *(ushort8v*)&As[(sr)      * LDT + sc] = a0;
        *(ushort8v*)&As[(sr + 32) * LDT + sc] = a1;
        *(ushort8v*)&Bs[(sr)      * LDT + sc] = b0;
        *(ushort8v*)&Bs[(sr + 32) * LDT + sc] = b1;
        __syncthreads();

#pragma unroll
        for (int ks = 0; ks < GBK; ks += 32) {
            bf16x8 af0 = *(const bf16x8*)&As[(wm + frow)      * LDT + ks + fk];
            bf16x8 af1 = *(const bf16x8*)&As[(wm + 16 + frow) * LDT + ks + fk];
            bf16x8 bv0 = *(const bf16x8*)&Bs[(wn + frow)      * LDT + ks + fk];
            bf16x8 bv1 = *(const bf16x8*)&Bs[(wn + 16 + frow) * LDT + ks + fk];
            acc00 = __builtin_amdgcn_mfma_f32_16x16x32_bf16(af0, bv0, acc00, 0, 0, 0);
            acc01 = __builtin_amdgcn_mfma_f32_16x16x32_bf16(af0, bv1, acc01, 0, 0, 0);
            acc10 = __builtin_amdgcn_mfma_f32_16x16x32_bf16(af1, bv0, acc10, 0, 0, 0);
            acc11 = __builtin_amdgcn_mfma_f32_16x16x32_bf16(af1, bv1, acc11, 0, 0, 0);
        }
    }

    float* out = Hp + (size_t)blockIdx.z * S * D;
    const int orow = (lane >> 4) * 4;   // + reg index
    const int ocol = lane & 15;
#pragma unroll
    for (int r = 0; r < 4; ++r) {
        out[(size_t)(m0 + wm +      orow + r) * D + n0 + wn +      ocol] = acc00[r];
        out[(size_t)(m0 + wm +      orow + r) * D + n0 + wn + 16 + ocol] = acc01[r];
        out[(size_t)(m0 + wm + 16 + orow + r) * D + n0 + wn +      ocol] = acc10[r];
        out[(size_t)(m0 + wm + 16 + orow + r) * D + n0 + wn + 16 + ocol] = acc11[r];
    }
}

// Reduce GSPLIT split-K partials + bias, then LayerNorm + affine + LeakyReLU.
__global__ __launch_bounds__(128) void ln_kernel(
    const float* __restrict__ Hp, const float* __restrict__ bias,
    const float* __restrict__ gamma, const float* __restrict__ beta,
    float* __restrict__ out, int S) {
    const int row = blockIdx.x;
    const int tid = threadIdx.x;
    const size_t idx = (size_t)row * 128 + tid;  // float4 index into [S,D]
    const size_t stride = (size_t)S * 128;       // float4 stride per partial

    const float4* hp = (const float4*)Hp;
    float4 v0 = hp[idx];
    float4 v1 = hp[idx + stride];
    float4 v2 = hp[idx + 2 * stride];
    float4 v3 = hp[idx + 3 * stride];
    float4 bb = *(const float4*)&bias[4 * tid];
    float4 v;
    v.x = (v0.x + v1.x) + (v2.x + v3.x) + bb.x;
    v.y = (v0.y + v1.y) + (v2.y + v3.y) + bb.y;
    v.z = (v0.z + v1.z) + (v2.z + v3.z) + bb.z;
    v.w = (v0.w + v1.w) + (v2.w + v3.w) + bb.w;

    float s = v.x + v.y + v.z + v.w;
    float q = v.x * v.x + v.y * v.y + v.z * v.z + v.w * v.w;
#pragma unroll
    for (int off = 32; off > 0; off >>= 1) {
        s += __shfl_down(s, off);
        q += __shfl_down(q, off);
    }
    __shared__ float ls[2], lq[2];
    const int wave = tid >> 6, lane = tid & 63;
    if (lane == 0) { ls[wave] = s; lq[wave] = q; }
    __syncthreads();
    s = ls[0] + ls[1];
    q = lq[0] + lq[1];

    const float mu = s * (1.f / 512.f);
    float var = q * (1.f / 512.f) - mu * mu;
    var = fmaxf(var, 0.f);
    const float r = rsqrtf(var + 1e-5f);

    float4 g  = *(const float4*)&gamma[4 * tid];
    float4 bt = *(const float4*)&beta[4 * tid];
    float4 o;
    o.x = (v.x - mu) * r * g.x + bt.x;
    o.y = (v.y - mu) * r * g.y + bt.y;
    o.z = (v.z - mu) * r * g.z + bt.z;
    o.w = (v.w - mu) * r * g.w + bt.w;
    o.x = o.x >= 0.f ? o.x : 0.01f * o.x;
    o.y = o.y >= 0.f ? o.y : 0.01f * o.y;
    o.z = o.z >= 0.f ? o.z : 0.01f * o.z;
    o.w = o.w >= 0.f ? o.w : 0.01f * o.w;
    *(float4*)&out[(size_t)row * D + 4 * tid] = o;
}

extern "C" void kernel_launch(void* const* d_in, const int* in_sizes, int n_in,
                              void* d_out, int out_size, void* d_ws, size_t ws_size,
                              hipStream_t stream) {
    const float* x     = (const float*)d_in[0];
    const float* W     = (const float*)d_in[1];
    const float* b     = (const float*)d_in[2];
    const float* gamma = (const float*)d_in[3];
    const float* beta  = (const float*)d_in[4];
    const int*   batch = (const int*)d_in[5];
    const int n = in_sizes[5];
    const int S = out_size / D;  // 1024

    char* ws = (char*)d_ws;
    unsigned short* pooled_b = (unsigned short*)ws;                       // [S,1536] bf16, 3 MB
    unsigned short* Wt       = (unsigned short*)(ws + (size_t)S * K3D * 2);          // [512,1536] bf16
    float*          Hp       = (float*)(ws + (size_t)S * K3D * 2 + (size_t)D * K3D * 2);  // [GSPLIT,S,512] f32
    int*            bounds   = (int*)(ws + (size_t)S * K3D * 2 + (size_t)D * K3D * 2
                                         + (size_t)GSPLIT * S * D * 4);   // [S+1] int
    float* out = (float*)d_out;

    bounds_kernel<<<(S + 1 + 255) / 256, 256, 0, stream>>>(batch, bounds, n, S);
    // pool blocks [0,S) + wconv blocks [S, S+384)
    pool_wconv_kernel<<<S + (K3D / 64) * (D / 32), 512, 0, stream>>>(
        x, bounds, pooled_b, W, Wt, S);
    dim3 gg(D / GBN, S / GBM, GSPLIT);  // (8, 16, 4)
    mfma_gemm<<<gg, 256, 0, stream>>>(pooled_b, Wt, Hp, S);
    ln_kernel<<<S, 128, 0, stream>>>(Hp, b, gamma, beta, out, S);
}